// Round 1
// baseline (368.488 us; speedup 1.0000x reference)
//
#include <hip/hip_runtime.h>
#include <hip/hip_bf16.h>
#include <stdint.h>

using f32x4  = __attribute__((ext_vector_type(4))) float;
using bf16x8 = __attribute__((ext_vector_type(8))) short;

constexpr int BATCH = 4;
constexpr int LQ_   = 256;
constexpr int LK_   = 50000;
constexpr int OUTD  = 256;   // OUT
constexpr int EIN   = 128;   // EDGE_IN
constexpr int KB    = 64;    // k-rows per block
constexpr int NKB   = (LK_ + KB - 1) / KB;   // 782 (last block: 16 valid rows)

__device__ __forceinline__ ushort f2bf(float f) {
  uint32_t u = __builtin_bit_cast(uint32_t, f);
  u = (u + 0x7fffu + ((u >> 16) & 1u)) >> 16;
  return (ushort)u;
}

// ---- prep: Gn[b] = (1/16) * (query[b] @ Wq^T + bq) @ Wk   -> bf16 ----------
// grid: BATCH*16 blocks x 256 thr; each block does 16 q-rows. bk dropped
// (per-row constant shift -> softmax invariant).
__global__ __launch_bounds__(256) void prep_qgn(
    const float* __restrict__ query, const float* __restrict__ Wq,
    const float* __restrict__ bq,    const float* __restrict__ Wk,
    ushort* __restrict__ Gn)
{
  __shared__ float qin[16 * EIN];    // 8 KB
  __shared__ float Qr [16 * OUTD];   // 16 KB
  const int blk = blockIdx.x;
  const int b = blk >> 4, q0 = (blk & 15) * 16;
  const int tid = threadIdx.x;

  { // stage 16 query rows (f32)
    int idx = tid * 8;
    int row = idx >> 7, c = idx & 127;
    const float* p = query + ((size_t)b * LQ_ + q0 + row) * EIN + c;
    float4 a = *(const float4*)p;
    float4 d = *(const float4*)(p + 4);
    float* q = &qin[row * EIN + c];
    q[0]=a.x; q[1]=a.y; q[2]=a.z; q[3]=a.w; q[4]=d.x; q[5]=d.y; q[6]=d.z; q[7]=d.w;
  }
  __syncthreads();

  // Q[q0+i][tid] = bq[tid] + sum_din qin[i][din]*Wq[tid][din]
  float acc[16];
  {
    float bias = bq[tid];
#pragma unroll
    for (int i = 0; i < 16; ++i) acc[i] = bias;
  }
  for (int din = 0; din < EIN; ++din) {
    float w = Wq[tid * EIN + din];
#pragma unroll
    for (int i = 0; i < 16; ++i) acc[i] += qin[i * EIN + din] * w;
  }
#pragma unroll
  for (int i = 0; i < 16; ++i) Qr[i * OUTD + tid] = acc[i];
  __syncthreads();

  // Gn[q0+i][tid] = norm * sum_d Q[i][d] * Wk[d][tid]
  float acc2[16];
#pragma unroll
  for (int i = 0; i < 16; ++i) acc2[i] = 0.f;
  for (int d = 0; d < OUTD; ++d) {
    float w = Wk[d * OUTD + tid];
#pragma unroll
    for (int i = 0; i < 16; ++i) acc2[i] += Qr[i * OUTD + d] * w;
  }
  const float norm = 0.0625f;   // 1/sqrt(256)
#pragma unroll
  for (int i = 0; i < 16; ++i)
    Gn[((size_t)b * LQ_ + q0 + i) * OUTD + tid] = f2bf(acc2[i] * norm);
}

__global__ __launch_bounds__(256) void cast_wv(const float* __restrict__ Wv,
                                               ushort* __restrict__ o) {
  int i = blockIdx.x * 256 + threadIdx.x;   // grid 256 -> 65536 elements
  o[i] = f2bf(Wv[i]);
}

// ---- main: per block (b, 64 k-rows): S = Gn@Ain^T, Vt = Wv@Ain^T (shared B),
// epilogue: den[q] += sum_k exp(S[q,k]); num[q] += sum_k exp(S[q,k])*Vt[q,k].
__global__ __launch_bounds__(256, 2) void attn_main(
    const float*  __restrict__ input, const ushort* __restrict__ Gn,
    const ushort* __restrict__ Wvbf,  float* __restrict__ num,
    float* __restrict__ den)
{
  __shared__ ushort Ain[KB * 256];   // 32 KB, byte-XOR-swizzled bf16
  char* lds = (char*)Ain;
  const int blk = blockIdx.x;
  const int b = blk / NKB, kb = blk % NKB;
  const int k0 = kb * KB;
  const int tid = threadIdx.x;

  // ---- stage input[b, k0:k0+KB, :] f32 -> bf16 LDS (swizzled), zero-pad OOB
  const float* src = input + (size_t)b * LK_ * 256;
  for (int i = 0; i < 8; ++i) {
    int chunk = i * 256 + tid;        // 2048 chunks of 8 f32
    int row = chunk >> 5;             // 32 chunks per 256-wide row
    int c8  = (chunk & 31) * 8;
    int krow = k0 + row;
    float4 v0 = {0,0,0,0}, v1 = {0,0,0,0};
    if (krow < LK_) {
      const float4* p = (const float4*)(src + (size_t)krow * 256 + c8);
      v0 = p[0]; v1 = p[1];
    }
    uint32_t p0 = (uint32_t)f2bf(v0.x) | ((uint32_t)f2bf(v0.y) << 16);
    uint32_t p1 = (uint32_t)f2bf(v0.z) | ((uint32_t)f2bf(v0.w) << 16);
    uint32_t p2 = (uint32_t)f2bf(v1.x) | ((uint32_t)f2bf(v1.y) << 16);
    uint32_t p3 = (uint32_t)f2bf(v1.z) | ((uint32_t)f2bf(v1.w) << 16);
    int byte = (row * 512 + c8 * 2) ^ ((row & 7) << 4);
    uint4 pk; pk.x = p0; pk.y = p1; pk.z = p2; pk.w = p3;
    *(uint4*)(lds + byte) = pk;
  }
  __syncthreads();

  const int w = tid >> 6, l = tid & 63, g = l >> 4, lr = l & 15;
  const ushort* GnB = Gn + (size_t)b * LQ_ * OUTD;

  float denA[4][4], numA[4][4];
#pragma unroll
  for (int mt = 0; mt < 4; ++mt)
#pragma unroll
    for (int r = 0; r < 4; ++r) { denA[mt][r] = 0.f; numA[mt][r] = 0.f; }

#pragma unroll
  for (int mt = 0; mt < 4; ++mt) {
    const int arow = w * 64 + mt * 16 + lr;          // A-operand row (q)
    const ushort* gp = GnB  + (size_t)arow * 256 + g * 8;
    const ushort* vp = Wvbf + (size_t)arow * 256 + g * 8;
    bf16x8 ga[8], wa[8];
#pragma unroll
    for (int kk = 0; kk < 8; ++kk) {
      ga[kk] = *(const bf16x8*)(gp + kk * 32);
      wa[kk] = *(const bf16x8*)(vp + kk * 32);
    }
#pragma unroll
    for (int nt = 0; nt < 4; ++nt) {
      f32x4 aS = {0,0,0,0}, aV = {0,0,0,0};
#pragma unroll
      for (int kk = 0; kk < 8; ++kk) {
        int r2 = nt * 16 + lr;                       // B-operand row (k)
        int byte = (r2 * 512 + (kk * 32 + g * 8) * 2) ^ ((r2 & 7) << 4);
        bf16x8 bf = *(const bf16x8*)(lds + byte);
        aS = __builtin_amdgcn_mfma_f32_16x16x32_bf16(ga[kk], bf, aS, 0, 0, 0);
        aV = __builtin_amdgcn_mfma_f32_16x16x32_bf16(wa[kk], bf, aV, 0, 0, 0);
      }
      // D frag: col(k)=lr, row(q)=4g+r. Scores bounded (~|S|<3): no max needed.
      int kidx = k0 + nt * 16 + lr;
      bool valid = kidx < LK_;
#pragma unroll
      for (int r = 0; r < 4; ++r) {
        float e = valid ? __expf(aS[r]) : 0.f;
        denA[mt][r] += e;
        numA[mt][r] += e * aV[r];
      }
    }
  }

  // row-sum across the 16 k-lanes, then one atomic per (q, {num,den})
#pragma unroll
  for (int mt = 0; mt < 4; ++mt) {
#pragma unroll
    for (int r = 0; r < 4; ++r) {
      float d_ = denA[mt][r], n_ = numA[mt][r];
#pragma unroll
      for (int m = 1; m < 16; m <<= 1) {
        d_ += __shfl_xor(d_, m, 64);
        n_ += __shfl_xor(n_, m, 64);
      }
      if (lr == 0) {
        int q = w * 64 + mt * 16 + g * 4 + r;
        atomicAdd(&den[b * OUTD + q], d_);
        atomicAdd(&num[b * OUTD + q], n_);
      }
    }
  }
}

// ---- finalize: out = num/den + bv  (V-bias deferred: num_true = num + bv*den)
__global__ __launch_bounds__(256) void finalize(const float* __restrict__ num,
                                                const float* __restrict__ den,
                                                const float* __restrict__ bv,
                                                float* __restrict__ out) {
  int i = blockIdx.x * 256 + threadIdx.x;   // 1024
  out[i] = num[i] / den[i] + bv[i & 255];
}

extern "C" void kernel_launch(void* const* d_in, const int* in_sizes, int n_in,
                              void* d_out, int out_size, void* d_ws, size_t ws_size,
                              hipStream_t stream)
{
  const float* query = (const float*)d_in[0];
  const float* input = (const float*)d_in[1];
  const float* Wq    = (const float*)d_in[2];
  const float* bq    = (const float*)d_in[3];
  const float* Wk    = (const float*)d_in[4];
  // d_in[5] = bk : softmax-invariant, unused
  const float* Wv    = (const float*)d_in[6];
  const float* bv    = (const float*)d_in[7];
  float* out = (float*)d_out;

  char* ws = (char*)d_ws;
  ushort* Gn   = (ushort*)ws;                       // 4*256*256*2 = 512 KB
  ushort* Wvbf = (ushort*)(ws + 524288);            // 128 KB
  float*  num  = (float*)(ws + 524288 + 131072);    // 4 KB
  float*  den  = num + BATCH * OUTD;                // 4 KB

  hipMemsetAsync(num, 0, 2 * BATCH * OUTD * sizeof(float), stream);
  prep_qgn<<<BATCH * 16, 256, 0, stream>>>(query, Wq, bq, Wk, Gn);
  cast_wv<<<256, 256, 0, stream>>>(Wv, Wvbf);
  attn_main<<<BATCH * NKB, 256, 0, stream>>>(input, Gn, Wvbf, num, den);
  finalize<<<BATCH, 256, 0, stream>>>(num, den, bv, out);
}

// Round 2
// 120.384 us; speedup vs baseline: 3.0609x; 3.0609x over previous
//
#include <hip/hip_runtime.h>
#include <hip/hip_bf16.h>
#include <stdint.h>

using f32x4  = __attribute__((ext_vector_type(4))) float;
using f32x16 = __attribute__((ext_vector_type(16))) float;
using bf16x8 = __attribute__((ext_vector_type(8))) short;

constexpr int BATCH = 4;
constexpr int LQ_   = 256;
constexpr int LK_   = 50000;
constexpr int OUTD  = 256;
constexpr int EIN   = 128;
constexpr int KB    = 64;                     // k-rows per tile
constexpr int NKB   = (LK_ + KB - 1) / KB;    // 782
constexpr int BPB   = 64;                     // blocks per batch (grid = 256 = 1/CU)

__device__ __forceinline__ ushort f2bf(float f) {
  uint32_t u = __builtin_bit_cast(uint32_t, f);
  u = (u + 0x7fffu + ((u >> 16) & 1u)) >> 16;
  return (ushort)u;
}
__device__ __forceinline__ short bfr(float f) {   // RNE via HIP type (cvt_pk-fusable)
  __hip_bfloat16 h = __float2bfloat16(f);
  return __builtin_bit_cast(short, h);
}

// ---- prep: Gn[b] = (1/16) * (query[b] @ Wq^T + bq) @ Wk   -> bf16 ----------
__global__ __launch_bounds__(256) void prep_qgn(
    const float* __restrict__ query, const float* __restrict__ Wq,
    const float* __restrict__ bq,    const float* __restrict__ Wk,
    ushort* __restrict__ Gn)
{
  __shared__ float qin[16 * EIN];
  __shared__ float Qr [16 * OUTD];
  const int blk = blockIdx.x;
  const int b = blk >> 4, q0 = (blk & 15) * 16;
  const int tid = threadIdx.x;

  {
    int idx = tid * 8;
    int row = idx >> 7, c = idx & 127;
    const float* p = query + ((size_t)b * LQ_ + q0 + row) * EIN + c;
    float4 a = *(const float4*)p;
    float4 d = *(const float4*)(p + 4);
    float* q = &qin[row * EIN + c];
    q[0]=a.x; q[1]=a.y; q[2]=a.z; q[3]=a.w; q[4]=d.x; q[5]=d.y; q[6]=d.z; q[7]=d.w;
  }
  __syncthreads();

  float acc[16];
  {
    float bias = bq[tid];
#pragma unroll
    for (int i = 0; i < 16; ++i) acc[i] = bias;
  }
  for (int din = 0; din < EIN; ++din) {
    float w = Wq[tid * EIN + din];
#pragma unroll
    for (int i = 0; i < 16; ++i) acc[i] += qin[i * EIN + din] * w;
  }
#pragma unroll
  for (int i = 0; i < 16; ++i) Qr[i * OUTD + tid] = acc[i];
  __syncthreads();

  float acc2[16];
#pragma unroll
  for (int i = 0; i < 16; ++i) acc2[i] = 0.f;
  for (int d = 0; d < OUTD; ++d) {
    float w = Wk[d * OUTD + tid];
#pragma unroll
    for (int i = 0; i < 16; ++i) acc2[i] += Qr[i * OUTD + d] * w;
  }
  const float norm = 0.0625f;
#pragma unroll
  for (int i = 0; i < 16; ++i)
    Gn[((size_t)b * LQ_ + q0 + i) * OUTD + tid] = f2bf(acc2[i] * norm);
}

__global__ __launch_bounds__(256) void cast_wv(const float* __restrict__ Wv,
                                               ushort* __restrict__ o) {
  int i = blockIdx.x * 256 + threadIdx.x;
  o[i] = f2bf(Wv[i]);
}

// ---- main --------------------------------------------------------------
// 256 blocks (1/CU), 512 thr (8 waves). Wave w owns q-rows [w*32, w*32+32).
// Persistent A-frags (Gn, Wv) in regs; grid-stride over k-tiles of 64 rows.
// LDS: f32 double-buffer, layout [16 Kstep][64 row][16 feats(64B)] per buffer
//  -> global_load_lds dest is linear lane*16; ds_read_b128 covers each granule
//     exactly once per wave -> conflict-free both sides.
__global__ __launch_bounds__(512, 2) void attn_main(
    const float*  __restrict__ input, const ushort* __restrict__ Gn,
    const ushort* __restrict__ Wvbf,  float* __restrict__ num,
    float* __restrict__ den)
{
  __shared__ float ldsf[2 * 16384];   // 128 KB
  const int b = blockIdx.x >> 6, blk = blockIdx.x & (BPB - 1);
  const int t0 = (blk * NKB) >> 6, t1 = ((blk + 1) * NKB) >> 6;
  const int tid = threadIdx.x, w = tid >> 6, l = tid & 63;
  const float* src = input + (size_t)b * LK_ * 256;

  // persistent A fragments: 16 K-steps each for Gn (S-gemm) and Wv (V-gemm)
  const int arow = w * 32 + (l & 31);
  const ushort* gp = Gn   + ((size_t)b * LQ_ + arow) * 256 + (l >> 5) * 8;
  const ushort* vp = Wvbf + (size_t)arow * 256 + (l >> 5) * 8;
  bf16x8 ga[16], wa[16];
#pragma unroll
  for (int k = 0; k < 16; ++k) {
    ga[k] = *(const bf16x8*)(gp + k * 16);
    wa[k] = *(const bf16x8*)(vp + k * 16);
  }

  float numr[16], denr[16];
#pragma unroll
  for (int r = 0; r < 16; ++r) { numr[r] = 0.f; denr[r] = 0.f; }

  // stage tile t -> buffer buf (async, direct-to-LDS, 8 instrs/wave)
  auto stage = [&](int t, int buf) {
#pragma unroll
    for (int i = 0; i < 8; ++i) {
      int c  = w * 8 + i;              // chunk 0..63 (1 KB each)
      int Ks = c >> 2, rq = c & 3;
      int row = t * KB + rq * 16 + (l >> 2);
      row = row < LK_ ? row : LK_ - 1;             // clamp (masked in epilogue)
      const float* g = src + (size_t)row * 256 + Ks * 16 + (l & 3) * 4;
      char* ldsb = (char*)ldsf + buf * 65536 + c * 1024;
      __builtin_amdgcn_global_load_lds(
          (const __attribute__((address_space(1))) void*)g,
          (__attribute__((address_space(3))) void*)ldsb, 16, 0, 0);
    }
  };

  stage(t0, 0);
  __syncthreads();

  for (int t = t0; t < t1; ++t) {
    const int p = (t - t0) & 1;
    if (t + 1 < t1) stage(t + 1, p ^ 1);
    const char* base = (const char*)ldsf + p * 65536;

#pragma unroll 1
    for (int ct = 0; ct < 2; ++ct) {
      f32x16 aS = {0,0,0,0,0,0,0,0,0,0,0,0,0,0,0,0};
      f32x16 aV = {0,0,0,0,0,0,0,0,0,0,0,0,0,0,0,0};
#pragma unroll
      for (int ks = 0; ks < 16; ++ks) {
        const char* addr = base + ks * 4096 + (ct * 32 + (l & 31)) * 64 + (l >> 5) * 32;
        f32x4 x0 = *(const f32x4*)addr;
        f32x4 x1 = *(const f32x4*)(addr + 16);
        bf16x8 bb;
        bb[0] = bfr(x0[0]); bb[1] = bfr(x0[1]); bb[2] = bfr(x0[2]); bb[3] = bfr(x0[3]);
        bb[4] = bfr(x1[0]); bb[5] = bfr(x1[1]); bb[6] = bfr(x1[2]); bb[7] = bfr(x1[3]);
        aS = __builtin_amdgcn_mfma_f32_32x32x16_bf16(ga[ks], bb, aS, 0, 0, 0);
        aV = __builtin_amdgcn_mfma_f32_32x32x16_bf16(wa[ks], bb, aV, 0, 0, 0);
      }
      const int krow = t * KB + ct * 32 + (l & 31);
      const bool valid = krow < LK_;
#pragma unroll
      for (int r = 0; r < 16; ++r) {
        float e = valid ? __expf(aS[r]) : 0.f;
        denr[r] += e;
        numr[r] += e * aV[r];
      }
    }
    __syncthreads();   // drains stage loads (vmcnt0) + guards buffer swap
  }

  // reduce over the 32 k-columns (lanes l&31), then atomics
#pragma unroll
  for (int r = 0; r < 16; ++r) {
    float d_ = denr[r], n_ = numr[r];
#pragma unroll
    for (int m = 1; m < 32; m <<= 1) {
      d_ += __shfl_xor(d_, m, 64);
      n_ += __shfl_xor(n_, m, 64);
    }
    if ((l & 31) == 0) {
      int q = w * 32 + (r & 3) + 8 * (r >> 2) + 4 * (l >> 5);
      atomicAdd(&den[b * OUTD + q], d_);
      atomicAdd(&num[b * OUTD + q], n_);
    }
  }
}

// ---- finalize: out = num/den + bv ------------------------------------------
__global__ __launch_bounds__(256) void finalize(const float* __restrict__ num,
                                                const float* __restrict__ den,
                                                const float* __restrict__ bv,
                                                float* __restrict__ out) {
  int i = blockIdx.x * 256 + threadIdx.x;
  out[i] = num[i] / den[i] + bv[i & 255];
}

extern "C" void kernel_launch(void* const* d_in, const int* in_sizes, int n_in,
                              void* d_out, int out_size, void* d_ws, size_t ws_size,
                              hipStream_t stream)
{
  const float* query = (const float*)d_in[0];
  const float* input = (const float*)d_in[1];
  const float* Wq    = (const float*)d_in[2];
  const float* bq    = (const float*)d_in[3];
  const float* Wk    = (const float*)d_in[4];
  // d_in[5] = bk : softmax-invariant, unused
  const float* Wv    = (const float*)d_in[6];
  const float* bv    = (const float*)d_in[7];
  float* out = (float*)d_out;

  char* ws = (char*)d_ws;
  ushort* Gn   = (ushort*)ws;                       // 512 KB
  ushort* Wvbf = (ushort*)(ws + 524288);            // 128 KB
  float*  num  = (float*)(ws + 524288 + 131072);
  float*  den  = num + BATCH * OUTD;

  hipMemsetAsync(num, 0, 2 * BATCH * OUTD * sizeof(float), stream);
  prep_qgn<<<BATCH * 16, 256, 0, stream>>>(query, Wq, bq, Wk, Gn);
  cast_wv<<<256, 256, 0, stream>>>(Wv, Wvbf);
  attn_main<<<BATCH * BPB, 512, 0, stream>>>(input, Gn, Wvbf, num, den);
  finalize<<<BATCH, 256, 0, stream>>>(num, den, bv, out);
}